// Round 9
// baseline (2963.688 us; speedup 1.0000x reference)
//
#include <hip/hip_runtime.h>
#include <hip/hip_cooperative_groups.h>

// VectorQuantizer (VAR-style multi-scale residual VQ) forward on gfx950.
// R9: cooperative mega-kernel, take 2. R8's coop launch silently failed
// (absmax == max|f_hat| -> output never written; return code unchecked;
// 4 blocks/CU co-residency demand too tight). Now: 512 blocks = 2/CU with
// __launch_bounds__(256,2) (no VGPR cap pressure), return code CHECKED with
// a full multi-launch fallback (same device bodies via wrappers).

namespace cg = cooperative_groups;

#define B_ 32
#define C_ 64
#define L_ 512
#define V_ 8192

typedef _Float16 half8 __attribute__((ext_vector_type(8)));
typedef float f32x4 __attribute__((ext_vector_type(4)));

#define C11 4.8828125e-4f  // 2^-11

__device__ __forceinline__ unsigned enc_f(float s) {
  unsigned u = __float_as_uint(s);
  return (u & 0x80000000u) ? ~u : (u | 0x80000000u);
}

__device__ __forceinline__ void split2(float x, _Float16& h, _Float16& m) {
  h = (_Float16)x;
  float r1 = x - (float)h;       // exact
  m = (_Float16)(r1 * 2048.0f);  // scaled into fp16 normal range
}

// ---------------- setup unit (u in [0,1024)) ----------------
__device__ __forceinline__ void setup_unit(
    int u, int tid, const float* __restrict__ f, const float* __restrict__ embed,
    _Float16* __restrict__ ch, _Float16* __restrict__ cm,
    float* __restrict__ restAll, float* __restrict__ lossac,
    unsigned long long* __restrict__ packed) {
  if (u < 128) {
    int g = u * 256 + tid;  // 4 lanes per code
    int v = g >> 2;
    int sub = g & 3;
    const float* row = embed + v * 64 + sub * 16;
    float x[16];
    float ss = 0.f;
#pragma unroll
    for (int i = 0; i < 16; i += 4) {
      float4 t = *(const float4*)(row + i);
      x[i] = t.x; x[i + 1] = t.y; x[i + 2] = t.z; x[i + 3] = t.w;
      ss += t.x * t.x + t.y * t.y + t.z * t.z + t.w * t.w;
    }
    ss += __shfl_xor(ss, 1);
    ss += __shfl_xor(ss, 2);
    float rinv = 1.0f / fmaxf(sqrtf(ss), 1e-12f);
    _Float16 hb[16], mb[16];
#pragma unroll
    for (int i = 0; i < 16; i++) split2(x[i] * rinv, hb[i], mb[i]);
    const int o = v * 64 + sub * 16;
    *(half8*)(ch + o) = *(half8*)(hb);
    *(half8*)(ch + o + 8) = *(half8*)(hb + 8);
    *(half8*)(cm + o) = *(half8*)(mb);
    *(half8*)(cm + o + 8) = *(half8*)(mb + 8);
  } else if (u < 640) {
    int sb = u - 128;  // 512 units: 32 b x 16 c-groups
    int b = sb >> 4;
    int c = (sb & 15) * 4 + (tid >> 6);
    int lane = tid & 63;
    const float* row = f + (b * 64 + c) * 512 + lane * 8;
    float4 x0 = *(const float4*)row;
    float4 x1 = *(const float4*)(row + 4);
    float ssum = ((x0.x + x0.y) + (x0.z + x0.w)) +
                 ((x1.x + x1.y) + (x1.z + x1.w));
#pragma unroll
    for (int off = 32; off > 0; off >>= 1) ssum += __shfl_down(ssum, off);
    if (lane == 0) restAll[c * 32 + b] = ssum;
  } else {
    int zg = (u - 640) * 256 + tid;
    const int ZS = 384 * 256;
    for (int i = zg; i < 126976; i += ZS) restAll[2048 + i] = 0.0f;
    for (int i = zg; i < 32736; i += ZS) packed[i] = 0ull;
    if (zg < 16) lossac[zg] = 0.0f;
  }
}

// ---------------- argmax phase (R6 body) ----------------
template <int MT>
__device__ __forceinline__ void argmax_phase(
    const _Float16* __restrict__ ch, const _Float16* __restrict__ cm,
    const float* __restrict__ restq, unsigned long long* __restrict__ packedq,
    int Q, int mgroups, int wave_codes, int bx, _Float16 (*qh)[72],
    _Float16 (*qm)[72]) {
  const int mg = bx % mgroups;
  const int sp = bx / mgroups;
  const int lane = threadIdx.x & 63;
  const int wave = threadIdx.x >> 6;
  const int qbase = mg * (MT * 16);
  for (int i = threadIdx.x; i < MT * 16 * 64; i += 256) {
    int c = i / (MT * 16);
    int qq = i % (MT * 16);
    float v = restq[c * Q + qbase + qq];
    _Float16 h, m;
    split2(v, h, m);
    qh[qq][c] = h;
    qm[qq][c] = m;
  }
  __syncthreads();

  const int m = lane & 15;
  const int quad = lane >> 4;
  half8 ah[MT][2], am[MT][2];
#pragma unroll
  for (int mt = 0; mt < MT; mt++)
#pragma unroll
    for (int kc = 0; kc < 2; kc++) {
      ah[mt][kc] = *(const half8*)(&qh[mt * 16 + m][kc * 32 + quad * 8]);
      am[mt][kc] = *(const half8*)(&qm[mt * 16 + m][kc * 32 + quad * 8]);
    }

  float best[MT][4];
  int bidx[MT][4];
#pragma unroll
  for (int mt = 0; mt < MT; mt++)
#pragma unroll
    for (int r = 0; r < 4; r++) { best[mt][r] = -3.4e38f; bidx[mt][r] = 0; }

  const int code_start = (sp * 4 + wave) * wave_codes;
  const _Float16* ph = ch + (code_start + m) * 64 + quad * 8;
  const _Float16* pm = cm + (code_start + m) * 64 + quad * 8;
  half8 nbh0 = *(const half8*)(ph);
  half8 nbh1 = *(const half8*)(ph + 32);
  half8 nbm0 = *(const half8*)(pm);
  half8 nbm1 = *(const half8*)(pm + 32);
  for (int t = 0; t < wave_codes; t += 16) {
    const half8 bh0 = nbh0, bh1 = nbh1, bm0 = nbm0, bm1 = nbm1;
    if (t + 16 < wave_codes) {
      ph += 16 * 64;
      pm += 16 * 64;
      nbh0 = *(const half8*)(ph);
      nbh1 = *(const half8*)(ph + 32);
      nbm0 = *(const half8*)(pm);
      nbm1 = *(const half8*)(pm + 32);
    }
    const int cid = code_start + t + m;
#pragma unroll
    for (int mt = 0; mt < MT; mt++) {
      f32x4 a0 = {0.f, 0.f, 0.f, 0.f};
      f32x4 a1 = {0.f, 0.f, 0.f, 0.f};
      a0 = __builtin_amdgcn_mfma_f32_16x16x32_f16(ah[mt][0], bh0, a0, 0, 0, 0);
      a1 = __builtin_amdgcn_mfma_f32_16x16x32_f16(ah[mt][0], bm0, a1, 0, 0, 0);
      a1 = __builtin_amdgcn_mfma_f32_16x16x32_f16(am[mt][0], bh0, a1, 0, 0, 0);
      a0 = __builtin_amdgcn_mfma_f32_16x16x32_f16(ah[mt][1], bh1, a0, 0, 0, 0);
      a1 = __builtin_amdgcn_mfma_f32_16x16x32_f16(ah[mt][1], bm1, a1, 0, 0, 0);
      a1 = __builtin_amdgcn_mfma_f32_16x16x32_f16(am[mt][1], bh1, a1, 0, 0, 0);
#pragma unroll
      for (int r = 0; r < 4; r++) {
        float sc = fmaf(C11, a1[r], a0[r]);
        if (sc > best[mt][r]) { best[mt][r] = sc; bidx[mt][r] = cid; }
      }
    }
  }
#pragma unroll
  for (int off = 1; off < 16; off <<= 1) {
#pragma unroll
    for (int mt = 0; mt < MT; mt++)
#pragma unroll
      for (int r = 0; r < 4; r++) {
        float ob = __shfl_xor(best[mt][r], off);
        int oi = __shfl_xor(bidx[mt][r], off);
        if (ob > best[mt][r] || (ob == best[mt][r] && oi < bidx[mt][r])) {
          best[mt][r] = ob; bidx[mt][r] = oi;
        }
      }
  }
  if (m == 0) {
#pragma unroll
    for (int mt = 0; mt < MT; mt++)
#pragma unroll
      for (int r = 0; r < 4; r++) {
        unsigned long long pk =
            ((unsigned long long)enc_f(best[mt][r]) << 32) |
            (unsigned)(~bidx[mt][r]);
        atomicMax(&packedq[qbase + mt * 16 + quad * 4 + r], pk);
      }
  }
}

// ---------------- fused phase (R6 body, w48 weights) ----------------
__device__ __forceinline__ void fused_phase(
    const float* __restrict__ f, const float* __restrict__ embed,
    const float* __restrict__ phiw, const float* __restrict__ phib,
    const unsigned long long* __restrict__ packedq, float* __restrict__ restn,
    float* __restrict__ fhat, float* __restrict__ lossac, int s, int log2blk,
    int pidx, int si, int log2blkn, int bx, float (*hl)[64],
    float (*abc_l)[192], float* red) {
  const int ch0 = (bx & 15) * 32;
  const int bb = bx >> 4;
  const int tid = threadIdx.x;
  const int blkw = 1 << log2blk;
  int j_lo = (ch0 >> log2blk) - 1;
  if (j_lo < 0) j_lo = 0;
  int j_hi = ((ch0 + 31) >> log2blk) + 1;
  if (j_hi > s - 1) j_hi = s - 1;
  const int nseg = j_hi - j_lo + 1;  // <= 34

  for (int i = tid; i < nseg * 64; i += 256) {
    int seg = i >> 6, c = i & 63;
    int idx = (int)(~(unsigned)(packedq[bb * s + j_lo + seg]));
    hl[seg][c] = embed[idx * 64 + c];
  }
  __syncthreads();

  {
    const int o = tid & 63;
    const int w4 = tid >> 6;
    const float* wrow = phiw + (pidx * 64 + o) * 192;  // [c][t] row
    float acc[9][3];
#pragma unroll
    for (int a = 0; a < 9; a++) { acc[a][0] = acc[a][1] = acc[a][2] = 0.f; }
#pragma unroll
    for (int c4b = 0; c4b < 4; c4b++) {
      float w48[48];
#pragma unroll
      for (int k = 0; k < 12; k++)
        *(float4*)(w48 + 4 * k) = *(const float4*)(wrow + c4b * 48 + 4 * k);
#pragma unroll
      for (int sx = 0; sx < 9; sx++) {
        int seg = w4 + sx * 4;
        if (seg < nseg) {
#pragma unroll
          for (int cc4 = 0; cc4 < 4; cc4++) {
            float4 h4 = *(const float4*)(&hl[seg][c4b * 16 + cc4 * 4]);
            const float hv[4] = {h4.x, h4.y, h4.z, h4.w};
#pragma unroll
            for (int u = 0; u < 4; u++) {
              int cc = cc4 * 4 + u;
              acc[sx][0] = fmaf(w48[cc * 3 + 0], hv[u], acc[sx][0]);
              acc[sx][1] = fmaf(w48[cc * 3 + 1], hv[u], acc[sx][1]);
              acc[sx][2] = fmaf(w48[cc * 3 + 2], hv[u], acc[sx][2]);
            }
          }
        }
      }
    }
#pragma unroll
    for (int sx = 0; sx < 9; sx++) {
      int seg = w4 + sx * 4;
      if (seg < nseg) {
        abc_l[seg][o] = acc[sx][0];
        abc_l[seg][64 + o] = acc[sx][1];
        abc_l[seg][128 + o] = acc[sx][2];
      }
    }
  }
  __syncthreads();

  const int c = tid >> 2;
  const int l0 = ch0 + (tid & 3) * 8;
  const float bias = phib[pidx * 64 + c];
  const int fi0 = (bb * 64 + c) * 512 + l0;
  const float4 fa = *(const float4*)(f + fi0);
  const float4 fb2 = *(const float4*)(f + fi0 + 4);
  float fv[8] = {fa.x, fa.y, fa.z, fa.w, fb2.x, fb2.y, fb2.z, fb2.w};
  float fhv[8] = {0.f, 0.f, 0.f, 0.f, 0.f, 0.f, 0.f, 0.f};
  if (si != 0) {
    const float4 ga = *(const float4*)(fhat + fi0);
    const float4 gb2 = *(const float4*)(fhat + fi0 + 4);
    fhv[0] = ga.x; fhv[1] = ga.y; fhv[2] = ga.z; fhv[3] = ga.w;
    fhv[4] = gb2.x; fhv[5] = gb2.y; fhv[6] = gb2.z; fhv[7] = gb2.w;
  }
  float dv[8];
  float sq = 0.f;
#pragma unroll
  for (int k = 0; k < 8; k++) {
    int l = l0 + k;
    int j = l >> log2blk;
    int jrel = j - j_lo;
    int pos = l & (blkw - 1);
    float y = abc_l[jrel][64 + c] + bias;
    if (pos == 0) {
      if (j > 0) y += abc_l[jrel - 1][c];
    } else {
      y += abc_l[jrel][c];
    }
    if (pos == blkw - 1) {
      if (j < s - 1) y += abc_l[jrel + 1][128 + c];
    } else {
      y += abc_l[jrel][128 + c];
    }
    float ho = 0.5f * (hl[jrel][c] + y);
    float fh = fhv[k] + ho;
    fhv[k] = fh;
    float d = fh - fv[k];
    dv[k] = d;
    sq = fmaf(d, d, sq);
  }
  *(float4*)(fhat + fi0) = make_float4(fhv[0], fhv[1], fhv[2], fhv[3]);
  *(float4*)(fhat + fi0 + 4) = make_float4(fhv[4], fhv[5], fhv[6], fhv[7]);

  if (log2blkn >= 0) {
    const int sn = 512 >> log2blkn;
    const int blkn = 1 << log2blkn;
    const int qb = c * (32 * sn) + bb * sn;
    if (blkn >= 16) {
      float rs = -(((dv[0] + dv[1]) + (dv[2] + dv[3])) +
                   ((dv[4] + dv[5]) + (dv[6] + dv[7])));
      atomicAdd(&restn[qb + (l0 >> log2blkn)], rs);
    } else if (blkn == 8) {
      float rs = -(((dv[0] + dv[1]) + (dv[2] + dv[3])) +
                   ((dv[4] + dv[5]) + (dv[6] + dv[7])));
      restn[qb + (l0 >> 3)] = rs;
    } else {
      for (int base = 0; base < 8; base += blkn) {
        float rs = 0.f;
        for (int k = 0; k < blkn; k++) rs += dv[base + k];
        restn[qb + ((l0 + base) >> log2blkn)] = -rs;
      }
    }
  }

#pragma unroll
  for (int off = 32; off > 0; off >>= 1) sq += __shfl_down(sq, off);
  const int lane = tid & 63, wave = tid >> 6;
  if (lane == 0) red[wave] = sq;
  __syncthreads();
  if (tid == 0)
    atomicAdd(&lossac[si], (red[0] + red[1]) + (red[2] + red[3]));
}

union SmemU {
  struct { _Float16 qh[64][72]; _Float16 qm[64][72]; } am;  // 18432 B
  struct { float hl[34][64]; float abc[34][192]; } fu;      // 34816 B
};

__device__ const int g_NS[10] = {128, 128, 128, 128, 64, 32, 16, 8, 4, 2};
__device__ const int g_PIDX[10] = {0, 0, 1, 1, 1, 2, 2, 3, 3, 3};

// ---------------- cooperative mega kernel: 512 blocks, 2/CU ----------------
__global__ __launch_bounds__(256, 2) void k_mega(
    const float* __restrict__ f, const float* __restrict__ embed,
    const float* __restrict__ phiw, const float* __restrict__ phib,
    _Float16* __restrict__ ch, _Float16* __restrict__ cm,
    float* __restrict__ restAll, float* __restrict__ lossac,
    unsigned long long* __restrict__ packed, float* __restrict__ fhat) {
  cg::grid_group grid = cg::this_grid();
  __shared__ SmemU sm;
  __shared__ float red[4];
  const int blk = blockIdx.x;
  const int tid = threadIdx.x;

  for (int u = blk; u < 1024; u += 512)
    setup_unit(u, tid, f, embed, ch, cm, restAll, lossac, packed);
  __threadfence();
  grid.sync();

#pragma unroll 1
  for (int si = 0; si < 10; si++) {
    const int s = 1 << si;
    const int Q = 32 * s;
    const int nsplit = g_NS[si];
    const int wave_codes = 2048 / nsplit;
    const int mgroups = (si == 0) ? 1 : (1 << (si - 1));
    const float* restq = restAll + 2048 * (s - 1);
    unsigned long long* pq = packed + 32 * (s - 1);

    if (blk < mgroups * nsplit) {
      if (si == 0)
        argmax_phase<2>(ch, cm, restq, pq, Q, 1, wave_codes, blk, sm.am.qh,
                        sm.am.qm);
      else
        argmax_phase<4>(ch, cm, restq, pq, Q, mgroups, wave_codes, blk,
                        sm.am.qh, sm.am.qm);
    }
    __threadfence();
    grid.sync();

    {
      float* restn = (si < 9) ? (restAll + 2048 * (2 * s - 1)) : nullptr;
      const int log2blkn = (si < 9) ? (8 - si) : -1;
      fused_phase(f, embed, phiw, phib, pq, restn, fhat, lossac, s, 9 - si,
                  g_PIDX[si], si, log2blkn, blk, sm.fu.hl, sm.fu.abc, red);
    }
    __threadfence();
    grid.sync();
  }

  if (blk == 0 && tid == 0) {
    float sum = 0.f;
    for (int i = 0; i < 10; i++) sum += lossac[i];
    fhat[B_ * C_ * L_] = sum * (1.25f / (10.0f * (float)(B_ * C_ * L_)));
  }
}

// ---------------- fallback wrappers (multi-launch path) ----------------
__global__ __launch_bounds__(256) void k_setup_f(
    const float* __restrict__ f, const float* __restrict__ embed,
    _Float16* __restrict__ ch, _Float16* __restrict__ cm,
    float* __restrict__ restAll, float* __restrict__ lossac,
    unsigned long long* __restrict__ packed) {
  setup_unit(blockIdx.x, threadIdx.x, f, embed, ch, cm, restAll, lossac,
             packed);
}

template <int MT>
__global__ __launch_bounds__(256) void k_argmax_f(
    const _Float16* __restrict__ ch, const _Float16* __restrict__ cm,
    const float* __restrict__ restq, unsigned long long* __restrict__ packedq,
    int Q, int mgroups, int wave_codes) {
  __shared__ _Float16 qh[64][72];
  __shared__ _Float16 qm[64][72];
  argmax_phase<MT>(ch, cm, restq, packedq, Q, mgroups, wave_codes, blockIdx.x,
                   qh, qm);
}

__global__ __launch_bounds__(256) void k_fused_f(
    const float* __restrict__ f, const float* __restrict__ embed,
    const float* __restrict__ phiw, const float* __restrict__ phib,
    const unsigned long long* __restrict__ packedq, float* __restrict__ restn,
    float* __restrict__ fhat, float* __restrict__ lossac, int s, int log2blk,
    int pidx, int si, int log2blkn) {
  __shared__ float hl[34][64];
  __shared__ float abc_l[34][192];
  __shared__ float red[4];
  fused_phase(f, embed, phiw, phib, packedq, restn, fhat, lossac, s, log2blk,
              pidx, si, log2blkn, blockIdx.x, hl, abc_l, red);
}

__global__ void k_loss_f(const float* __restrict__ lossac,
                         float* __restrict__ out) {
  if (threadIdx.x == 0 && blockIdx.x == 0) {
    float sum = 0.f;
    for (int i = 0; i < 10; i++) sum += lossac[i];
    out[B_ * C_ * L_] = sum * (1.25f / (10.0f * (float)(B_ * C_ * L_)));
  }
}

extern "C" void kernel_launch(void* const* d_in, const int* in_sizes, int n_in,
                              void* d_out, int out_size, void* d_ws,
                              size_t ws_size, hipStream_t stream) {
  const float* f     = (const float*)d_in[0];  // [32][64][512]
  const float* embed = (const float*)d_in[1];  // [8192][64]
  const float* phiw  = (const float*)d_in[2];  // [4][64][64][3]
  const float* phib  = (const float*)d_in[3];  // [4][64]
  float* fhat = (float*)d_out;                 // f_hat + loss at [1048576]

  _Float16* ch = (_Float16*)d_ws;                  // V*64
  _Float16* cm = ch + V_ * 64;
  float* restAll = (float*)(cm + V_ * 64);         // 2048*1023 floats
  float* lossac = restAll + 2048 * 1023;           // 16
  unsigned long long* packed = (unsigned long long*)(lossac + 16);  // 32736

  void* args[] = {(void*)&f,       (void*)&embed,  (void*)&phiw,
                  (void*)&phib,    (void*)&ch,     (void*)&cm,
                  (void*)&restAll, (void*)&lossac, (void*)&packed,
                  (void*)&fhat};
  hipError_t err = hipLaunchCooperativeKernel((const void*)k_mega, dim3(512),
                                              dim3(256), args, 0, stream);
  if (err != hipSuccess) {
    (void)hipGetLastError();  // clear sticky error, take multi-launch path
    static const int NS[10] = {128, 128, 128, 128, 64, 32, 16, 8, 4, 2};
    static const int PIDX[10] = {0, 0, 1, 1, 1, 2, 2, 3, 3, 3};
    k_setup_f<<<dim3(1024), dim3(256), 0, stream>>>(f, embed, ch, cm, restAll,
                                                    lossac, packed);
    for (int si = 0; si < 10; si++) {
      const int s = 1 << si;
      const int Q = 32 * s;
      const int nsplit = NS[si];
      const int wave_codes = 2048 / nsplit;
      const int mgroups = (si == 0) ? 1 : (1 << (si - 1));
      const float* restq = restAll + 2048 * (s - 1);
      unsigned long long* pq = packed + 32 * (s - 1);
      if (si == 0)
        k_argmax_f<2><<<dim3(nsplit), dim3(256), 0, stream>>>(
            ch, cm, restq, pq, Q, 1, wave_codes);
      else
        k_argmax_f<4><<<dim3(mgroups * nsplit), dim3(256), 0, stream>>>(
            ch, cm, restq, pq, Q, mgroups, wave_codes);
      float* restn = (si < 9) ? (restAll + 2048 * (2 * s - 1)) : nullptr;
      const int log2blkn = (si < 9) ? (8 - si) : -1;
      k_fused_f<<<dim3(512), dim3(256), 0, stream>>>(
          f, embed, phiw, phib, pq, restn, fhat, lossac, s, 9 - si, PIDX[si],
          si, log2blkn);
    }
    k_loss_f<<<dim3(1), dim3(64), 0, stream>>>(lossac, fhat);
  }
}

// Round 10
// 1219.814 us; speedup vs baseline: 2.4296x; 2.4296x over previous
//
#include <hip/hip_runtime.h>

// VectorQuantizer (VAR-style multi-scale residual VQ) forward on gfx950.
// R10: code-space telescoping. Queries per scale are generated from tiny
// 64-dim state (Sbulk bulk density at finest granularity; EL/ER boundary
// corrections) instead of re-materializing fhat each scale. fhat + all 10
// losses materialize ONCE in k_final (register-resident accumulation).
// Argmax kernels byte-identical to R6 (proven 102us @ s=512).
// Launches: prep, argmax0, 9x(qgen,argmax), final, loss = 22 (all non-argmax tiny).

#define B_ 32
#define C_ 64
#define L_ 512
#define V_ 8192

typedef _Float16 half8 __attribute__((ext_vector_type(8)));
typedef float f32x4 __attribute__((ext_vector_type(4)));

#define C11 4.8828125e-4f  // 2^-11

__device__ __forceinline__ unsigned enc_f(float s) {
  unsigned u = __float_as_uint(s);
  return (u & 0x80000000u) ? ~u : (u | 0x80000000u);
}

__device__ __forceinline__ void split2(float x, _Float16& h, _Float16& m) {
  h = (_Float16)x;
  float r1 = x - (float)h;       // exact
  m = (_Float16)(r1 * 2048.0f);  // scaled into fp16 normal range
}

// ---------- prep: codebook split + hierarchical f-sums + zero state ----------
__global__ __launch_bounds__(256) void k_prep(
    const float* __restrict__ f, const float* __restrict__ embed,
    _Float16* __restrict__ ch, _Float16* __restrict__ cm,
    float* __restrict__ Fall, float* __restrict__ Sb /*Sb,EL,ER contiguous*/,
    float* __restrict__ lossac, unsigned long long* __restrict__ packed) {
  const int blk = blockIdx.x;
  const int tid = threadIdx.x;
  if (blk < 128) {
    // normalize codebook rows (fp32), 2-way split, [V][64]  (R6-proven)
    int g = blk * 256 + tid;
    int v = g >> 2;
    int sub = g & 3;
    const float* row = embed + v * 64 + sub * 16;
    float x[16];
    float ss = 0.f;
#pragma unroll
    for (int i = 0; i < 16; i += 4) {
      float4 t = *(const float4*)(row + i);
      x[i] = t.x; x[i + 1] = t.y; x[i + 2] = t.z; x[i + 3] = t.w;
      ss += t.x * t.x + t.y * t.y + t.z * t.z + t.w * t.w;
    }
    ss += __shfl_xor(ss, 1);
    ss += __shfl_xor(ss, 2);
    float rinv = 1.0f / fmaxf(sqrtf(ss), 1e-12f);
    _Float16 hb[16], mb[16];
#pragma unroll
    for (int i = 0; i < 16; i++) split2(x[i] * rinv, hb[i], mb[i]);
    const int o = v * 64 + sub * 16;
    *(half8*)(ch + o) = *(half8*)(hb);
    *(half8*)(ch + o + 8) = *(half8*)(hb + 8);
    *(half8*)(cm + o) = *(half8*)(mb);
    *(half8*)(cm + o + 8) = *(half8*)(mb + 8);
  } else if (blk < 640) {
    // hierarchical sums of f for ALL scales: one wave per (b, c)
    int gw = (blk - 128) * 4 + (tid >> 6);  // [0,2048)
    int b = gw >> 6;
    int c = gw & 63;
    int lane = tid & 63;
    const float* row = f + (b * 64 + c) * 512 + lane * 8;
    float4 x0 = *(const float4*)row;
    float4 x1 = *(const float4*)(row + 4);
    // s=512 (blk 1): raw copy
    {
      int base = 1046528 + c * 16384 + b * 512 + lane * 8;
      *(float4*)(Fall + base) = x0;
      *(float4*)(Fall + base + 4) = x1;
    }
    // s=256 (blk 2)
    {
      int base = 522240 + c * 8192 + b * 256 + lane * 4;
      Fall[base + 0] = x0.x + x0.y;
      Fall[base + 1] = x0.z + x0.w;
      Fall[base + 2] = x1.x + x1.y;
      Fall[base + 3] = x1.z + x1.w;
    }
    float y0 = (x0.x + x0.y) + (x0.z + x0.w);
    float y1 = (x1.x + x1.y) + (x1.z + x1.w);
    // s=128 (blk 4)
    {
      int base = 260096 + c * 4096 + b * 128 + lane * 2;
      Fall[base + 0] = y0;
      Fall[base + 1] = y1;
    }
    float v6 = y0 + y1;
    Fall[129024 + c * 2048 + b * 64 + lane] = v6;  // s=64
    float v5 = v6 + __shfl_xor(v6, 1);
    if (!(lane & 1)) Fall[63488 + c * 1024 + b * 32 + (lane >> 1)] = v5;
    float v4 = v5 + __shfl_xor(v5, 2);
    if (!(lane & 3)) Fall[30720 + c * 512 + b * 16 + (lane >> 2)] = v4;
    float v3 = v4 + __shfl_xor(v4, 4);
    if (!(lane & 7)) Fall[14336 + c * 256 + b * 8 + (lane >> 3)] = v3;
    float v2 = v3 + __shfl_xor(v3, 8);
    if (!(lane & 15)) Fall[6144 + c * 128 + b * 4 + (lane >> 4)] = v2;
    float v1 = v2 + __shfl_xor(v2, 16);
    if (!(lane & 31)) Fall[2048 + c * 64 + b * 2 + (lane >> 5)] = v1;
    float v0 = v1 + __shfl_xor(v1, 32);
    if (lane == 0) Fall[c * 32 + b] = v0;
  } else {
    // zero Sb+EL+ER (contiguous 3,149,824 floats), packed, lossac
    int zg = (blk - 640) * 256 + tid;
    const int ZS = 256 * 256;
    for (int i = zg; i < 3149824; i += ZS) Sb[i] = 0.0f;
    for (int i = zg; i < 32736; i += ZS) packed[i] = 0ull;
    if (zg < 16) lossac[zg] = 0.0f;
  }
}

// ---------- MFMA argmax (R6 body, unchanged) ----------
template <int MT>
__global__ __launch_bounds__(256) void k_argmax3(
    const _Float16* __restrict__ ch, const _Float16* __restrict__ cm,
    const float* __restrict__ restq, unsigned long long* __restrict__ packedq,
    int Q, int mgroups, int wave_codes) {
  const int mg = blockIdx.x % mgroups;
  const int sp = blockIdx.x / mgroups;
  const int lane = threadIdx.x & 63;
  const int wave = threadIdx.x >> 6;
  const int qbase = mg * (MT * 16);
  __shared__ _Float16 qh[MT * 16][72];
  __shared__ _Float16 qm[MT * 16][72];
  for (int i = threadIdx.x; i < MT * 16 * 64; i += 256) {
    int c = i / (MT * 16);
    int qq = i % (MT * 16);
    float v = restq[c * Q + qbase + qq];
    _Float16 h, m;
    split2(v, h, m);
    qh[qq][c] = h;
    qm[qq][c] = m;
  }
  __syncthreads();

  const int m = lane & 15;
  const int quad = lane >> 4;
  half8 ah[MT][2], am[MT][2];
#pragma unroll
  for (int mt = 0; mt < MT; mt++)
#pragma unroll
    for (int kc = 0; kc < 2; kc++) {
      ah[mt][kc] = *(const half8*)(&qh[mt * 16 + m][kc * 32 + quad * 8]);
      am[mt][kc] = *(const half8*)(&qm[mt * 16 + m][kc * 32 + quad * 8]);
    }

  float best[MT][4];
  int bidx[MT][4];
#pragma unroll
  for (int mt = 0; mt < MT; mt++)
#pragma unroll
    for (int r = 0; r < 4; r++) { best[mt][r] = -3.4e38f; bidx[mt][r] = 0; }

  const int code_start = (sp * 4 + wave) * wave_codes;
  const _Float16* ph = ch + (code_start + m) * 64 + quad * 8;
  const _Float16* pm = cm + (code_start + m) * 64 + quad * 8;
  half8 nbh0 = *(const half8*)(ph);
  half8 nbh1 = *(const half8*)(ph + 32);
  half8 nbm0 = *(const half8*)(pm);
  half8 nbm1 = *(const half8*)(pm + 32);
  for (int t = 0; t < wave_codes; t += 16) {
    const half8 bh0 = nbh0, bh1 = nbh1, bm0 = nbm0, bm1 = nbm1;
    if (t + 16 < wave_codes) {
      ph += 16 * 64;
      pm += 16 * 64;
      nbh0 = *(const half8*)(ph);
      nbh1 = *(const half8*)(ph + 32);
      nbm0 = *(const half8*)(pm);
      nbm1 = *(const half8*)(pm + 32);
    }
    const int cid = code_start + t + m;
#pragma unroll
    for (int mt = 0; mt < MT; mt++) {
      f32x4 a0 = {0.f, 0.f, 0.f, 0.f};
      f32x4 a1 = {0.f, 0.f, 0.f, 0.f};
      a0 = __builtin_amdgcn_mfma_f32_16x16x32_f16(ah[mt][0], bh0, a0, 0, 0, 0);
      a1 = __builtin_amdgcn_mfma_f32_16x16x32_f16(ah[mt][0], bm0, a1, 0, 0, 0);
      a1 = __builtin_amdgcn_mfma_f32_16x16x32_f16(am[mt][0], bh0, a1, 0, 0, 0);
      a0 = __builtin_amdgcn_mfma_f32_16x16x32_f16(ah[mt][1], bh1, a0, 0, 0, 0);
      a1 = __builtin_amdgcn_mfma_f32_16x16x32_f16(ah[mt][1], bm1, a1, 0, 0, 0);
      a1 = __builtin_amdgcn_mfma_f32_16x16x32_f16(am[mt][1], bh1, a1, 0, 0, 0);
#pragma unroll
      for (int r = 0; r < 4; r++) {
        float sc = fmaf(C11, a1[r], a0[r]);
        if (sc > best[mt][r]) { best[mt][r] = sc; bidx[mt][r] = cid; }
      }
    }
  }
#pragma unroll
  for (int off = 1; off < 16; off <<= 1) {
#pragma unroll
    for (int mt = 0; mt < MT; mt++)
#pragma unroll
      for (int r = 0; r < 4; r++) {
        float ob = __shfl_xor(best[mt][r], off);
        int oi = __shfl_xor(bidx[mt][r], off);
        if (ob > best[mt][r] || (ob == best[mt][r] && oi < bidx[mt][r])) {
          best[mt][r] = ob; bidx[mt][r] = oi;
        }
      }
  }
  if (m == 0) {
#pragma unroll
    for (int mt = 0; mt < MT; mt++)
#pragma unroll
      for (int r = 0; r < 4; r++) {
        unsigned long long pk =
            ((unsigned long long)enc_f(best[mt][r]) << 32) |
            (unsigned)(~bidx[mt][r]);
        atomicMax(&packedq[qbase + mt * 16 + quad * 4 + r], pk);
      }
  }
}

// ---------- qgen: update state with scale k=i-1 results, emit queries q_i ----------
// Sb[b][slot(512)][64]: bulk density sum; EL/ER[b][beta(513)][64]: edge sums.
__global__ __launch_bounds__(256) void k_qgen(
    const float* __restrict__ embed, const float* __restrict__ phiw,
    const float* __restrict__ phib,
    const unsigned long long* __restrict__ packed, const float* __restrict__ Fall,
    float* __restrict__ q, float* __restrict__ Sb, float* __restrict__ EL,
    float* __restrict__ ER, float* __restrict__ scr, int i, int pk_) {
  const int b = blockIdx.x;
  const int tid = threadIdx.x;
  const int k = i - 1;
  const int sk = 1 << k;
  const int blkk = 512 >> k;
  const int log2blkk = 9 - k;
  __shared__ float hl[256][64];

  // stage h for all scale-k segments of batch b
  for (int idx = tid; idx < sk * 64; idx += 256) {
    int seg = idx >> 6, c = idx & 63;
    int w = (int)(~(unsigned)(packed[32 * (sk - 1) + b * sk + seg]));
    hl[seg][c] = embed[w * 64 + c];
  }
  __syncthreads();

  // A1: per-segment conv matvecs a0=W-1 h, a1=W0 h, a2=W+1 h -> scr
  {
    const int o = tid & 63;
    const float* wrow = phiw + (pk_ * 64 + o) * 192;
    for (int seg = tid >> 6; seg < sk; seg += 4) {
      float a0 = 0.f, a1 = 0.f, a2 = 0.f;
#pragma unroll
      for (int c4b = 0; c4b < 4; c4b++) {
        float w48[48];
#pragma unroll
        for (int kk = 0; kk < 12; kk++)
          *(float4*)(w48 + 4 * kk) = *(const float4*)(wrow + c4b * 48 + 4 * kk);
#pragma unroll
        for (int cc4 = 0; cc4 < 4; cc4++) {
          float4 h4 = *(const float4*)(&hl[seg][c4b * 16 + cc4 * 4]);
          const float hv[4] = {h4.x, h4.y, h4.z, h4.w};
#pragma unroll
          for (int u = 0; u < 4; u++) {
            int cc = cc4 * 4 + u;
            a0 = fmaf(w48[cc * 3 + 0], hv[u], a0);
            a1 = fmaf(w48[cc * 3 + 1], hv[u], a1);
            a2 = fmaf(w48[cc * 3 + 2], hv[u], a2);
          }
        }
      }
      float* sp_ = scr + (b * 256 + seg) * 192;
      sp_[o] = a0;
      sp_[64 + o] = a1;
      sp_[128 + o] = a2;
    }
  }
  __threadfence_block();
  __syncthreads();

  // A2: state updates
  // Sbulk: += 0.5*(h + a0+a1+a2 + bias) for every finest slot in each segment
  for (int idx = tid; idx < 512 * 64; idx += 256) {
    int slot = idx >> 6, c = idx & 63;
    int seg = slot >> log2blkk;
    const float* sp_ = scr + (b * 256 + seg) * 192;
    Sb[(b * 512 + slot) * 64 + c] +=
        0.5f * (hl[seg][c] + sp_[c] + sp_[64 + c] + sp_[128 + c] +
                phib[pk_ * 64 + c]);
  }
  // EL[beta=J*blkk] += 0.5*(a0[J-1] - a0[J])   (a0[-1]=0)
  for (int idx = tid; idx < sk * 64; idx += 256) {
    int J = idx >> 6, c = idx & 63;
    float lm = (J > 0) ? scr[(b * 256 + J - 1) * 192 + c] : 0.f;
    EL[(b * 513 + J * blkk) * 64 + c] +=
        0.5f * (lm - scr[(b * 256 + J) * 192 + c]);
  }
  // ER[beta=J*blkk] += 0.5*(a2[J] - a2[J-1]) for J=1..sk  (a2[sk]=0)
  for (int idx = tid; idx < sk * 64; idx += 256) {
    int J = (idx >> 6) + 1, c = idx & 63;
    float rc_ = (J < sk) ? scr[(b * 256 + J) * 192 + 128 + c] : 0.f;
    ER[(b * 513 + J * blkk) * 64 + c] +=
        0.5f * (rc_ - scr[(b * 256 + J - 1) * 192 + 128 + c]);
  }
  __threadfence_block();
  __syncthreads();

  // B: emit queries for scale i:
  // q[c][b*si + j] = Fsum_i - blki*Sb[l0] - EL[l0] - ER[l1+1]
  const int si_ = 1 << i;
  const int blki = 512 >> i;
  const int Q = 32 * si_;
  const int fo = 2048 * (si_ - 1);
  const float fblk = (float)blki;
  for (int idx = tid; idx < (si_ << 6); idx += 256) {
    int j = idx & (si_ - 1);
    int c = idx >> i;
    float val = Fall[fo + c * (32 * si_) + b * si_ + j] -
                fblk * Sb[(b * 512 + j * blki) * 64 + c] -
                EL[(b * 513 + j * blki) * 64 + c] -
                ER[(b * 513 + (j + 1) * blki) * 64 + c];
    q[c * Q + b * si_ + j] = val;
  }
}

// ---------- final: materialize fhat (registers) + all 10 losses ----------
__global__ __launch_bounds__(256) void k_final(
    const float* __restrict__ f, const float* __restrict__ embed,
    const float* __restrict__ phiw, const float* __restrict__ phib,
    const unsigned long long* __restrict__ packed, float* __restrict__ fhat,
    float* __restrict__ lossac) {
  const int ch0 = blockIdx.x * 64;
  const int bb = blockIdx.y;
  const int tid = threadIdx.x;
  __shared__ float hl[66][64];
  __shared__ float abc_l[66][192];
  __shared__ float red[4];

  const int c = tid >> 2;
  const int l0 = ch0 + (tid & 3) * 16;
  const int fi0 = (bb * 64 + c) * 512 + l0;
  float fv[16], fh[16];
#pragma unroll
  for (int t = 0; t < 4; t++) {
    float4 x = *(const float4*)(f + fi0 + t * 4);
    fv[t * 4] = x.x; fv[t * 4 + 1] = x.y; fv[t * 4 + 2] = x.z; fv[t * 4 + 3] = x.w;
  }
#pragma unroll
  for (int t = 0; t < 16; t++) fh[t] = 0.f;

  static const int PIDXd[10] = {0, 0, 1, 1, 1, 2, 2, 3, 3, 3};
  const int lane = tid & 63, wave = tid >> 6;

#pragma unroll 1
  for (int k = 0; k < 10; k++) {
    const int s = 1 << k;
    const int log2blk = 9 - k;
    const int blkw = 1 << log2blk;
    const int p = PIDXd[k];
    int j_lo = (ch0 >> log2blk) - 1;
    if (j_lo < 0) j_lo = 0;
    int j_hi = ((ch0 + 63) >> log2blk) + 1;
    if (j_hi > s - 1) j_hi = s - 1;
    const int nseg = j_hi - j_lo + 1;  // <= 66

    __syncthreads();  // protect LDS from previous scale's readers
    for (int idx = tid; idx < nseg * 64; idx += 256) {
      int seg = idx >> 6, cc = idx & 63;
      int w = (int)(~(unsigned)(packed[32 * (s - 1) + bb * s + j_lo + seg]));
      hl[seg][cc] = embed[w * 64 + cc];
    }
    __syncthreads();

    {
      const int o = tid & 63;
      const float* wrow = phiw + (p * 64 + o) * 192;
      for (int seg = tid >> 6; seg < nseg; seg += 4) {
        float a0 = 0.f, a1 = 0.f, a2 = 0.f;
#pragma unroll
        for (int c4b = 0; c4b < 4; c4b++) {
          float w48[48];
#pragma unroll
          for (int kk = 0; kk < 12; kk++)
            *(float4*)(w48 + 4 * kk) =
                *(const float4*)(wrow + c4b * 48 + 4 * kk);
#pragma unroll
          for (int cc4 = 0; cc4 < 4; cc4++) {
            float4 h4 = *(const float4*)(&hl[seg][c4b * 16 + cc4 * 4]);
            const float hv[4] = {h4.x, h4.y, h4.z, h4.w};
#pragma unroll
            for (int u = 0; u < 4; u++) {
              int cc = cc4 * 4 + u;
              a0 = fmaf(w48[cc * 3 + 0], hv[u], a0);
              a1 = fmaf(w48[cc * 3 + 1], hv[u], a1);
              a2 = fmaf(w48[cc * 3 + 2], hv[u], a2);
            }
          }
        }
        abc_l[seg][o] = a0;
        abc_l[seg][64 + o] = a1;
        abc_l[seg][128 + o] = a2;
      }
    }
    __syncthreads();

    const float bias = phib[p * 64 + c];
    float sq = 0.f;
#pragma unroll
    for (int t = 0; t < 16; t++) {
      int l = l0 + t;
      int j = l >> log2blk;
      int jrel = j - j_lo;
      int pos = l & (blkw - 1);
      float y = abc_l[jrel][64 + c] + bias;
      if (pos == 0) {
        if (j > 0) y += abc_l[jrel - 1][c];
      } else {
        y += abc_l[jrel][c];
      }
      if (pos == blkw - 1) {
        if (j < s - 1) y += abc_l[jrel + 1][128 + c];
      } else {
        y += abc_l[jrel][128 + c];
      }
      fh[t] += 0.5f * (hl[jrel][c] + y);
      float d = fh[t] - fv[t];
      sq = fmaf(d, d, sq);
    }
#pragma unroll
    for (int off = 32; off > 0; off >>= 1) sq += __shfl_down(sq, off);
    if (lane == 0) red[wave] = sq;
    __syncthreads();
    if (tid == 0)
      atomicAdd(&lossac[k], (red[0] + red[1]) + (red[2] + red[3]));
  }

#pragma unroll
  for (int t = 0; t < 4; t++)
    *(float4*)(fhat + fi0 + t * 4) =
        make_float4(fh[t * 4], fh[t * 4 + 1], fh[t * 4 + 2], fh[t * 4 + 3]);
}

// ---------- final loss scalar ----------
__global__ void k_loss(const float* __restrict__ lossac,
                       float* __restrict__ out) {
  if (threadIdx.x == 0 && blockIdx.x == 0) {
    float sum = 0.f;
    for (int i = 0; i < 10; i++) sum += lossac[i];
    out[B_ * C_ * L_] = sum * (1.25f / (10.0f * (float)(B_ * C_ * L_)));
  }
}

extern "C" void kernel_launch(void* const* d_in, const int* in_sizes, int n_in,
                              void* d_out, int out_size, void* d_ws,
                              size_t ws_size, hipStream_t stream) {
  const float* f     = (const float*)d_in[0];  // [32][64][512]
  const float* embed = (const float*)d_in[1];  // [8192][64]
  const float* phiw  = (const float*)d_in[2];  // [4][64][64][3]
  const float* phib  = (const float*)d_in[3];  // [4][64]
  float* fhat = (float*)d_out;                 // f_hat + loss at [1048576]

  float* Fall = (float*)d_ws;                       // 2,095,104
  float* qbuf = Fall + 2095104;                     // 1,048,576
  float* Sb   = qbuf + 1048576;                     // 1,048,576
  float* EL   = Sb + 1048576;                       // 1,050,624
  float* ER   = EL + 1050624;                       // 1,050,624
  float* scr  = ER + 1050624;                       // 1,572,864
  float* lossac = scr + 1572864;                    // 16
  unsigned long long* packed = (unsigned long long*)(lossac + 16);  // 32736
  _Float16* ch = (_Float16*)(packed + 32736);       // V*64
  _Float16* cm = ch + V_ * 64;                      // V*64

  static const int PIDX[10] = {0, 0, 1, 1, 1, 2, 2, 3, 3, 3};
  static const int NSPL[10] = {128, 128, 128, 64, 64, 32, 16, 16, 8, 4};

  k_prep<<<dim3(896), dim3(256), 0, stream>>>(f, embed, ch, cm, Fall, Sb,
                                              lossac, packed);

  for (int si = 0; si < 10; si++) {
    const int s = 1 << si;
    const int Q = 32 * s;
    const int nsplit = NSPL[si];
    const int wave_codes = 2048 / nsplit;
    unsigned long long* pq = packed + 32 * (s - 1);
    const float* restq;
    if (si == 0) {
      restq = Fall;  // Fsum slice for s=1 is the scale-0 query directly
    } else {
      k_qgen<<<dim3(32), dim3(256), 0, stream>>>(
          embed, phiw, phib, packed, Fall, qbuf, Sb, EL, ER, scr, si,
          PIDX[si - 1]);
      restq = qbuf;
    }
    if (Q >= 64) {
      const int mgroups = Q / 64;
      k_argmax3<4><<<dim3(mgroups * nsplit), dim3(256), 0, stream>>>(
          ch, cm, restq, pq, Q, mgroups, wave_codes);
    } else {
      k_argmax3<2><<<dim3(nsplit), dim3(256), 0, stream>>>(
          ch, cm, restq, pq, Q, 1, wave_codes);
    }
  }

  k_final<<<dim3(8, 32), dim3(256), 0, stream>>>(f, embed, phiw, phib, packed,
                                                 fhat, lossac);
  k_loss<<<dim3(1), dim3(64), 0, stream>>>(lossac, fhat);
}

// Round 11
// 894.884 us; speedup vs baseline: 3.3118x; 1.3631x over previous
//
#include <hip/hip_runtime.h>

// VectorQuantizer (VAR-style multi-scale residual VQ) forward on gfx950.
// R11: telescoped queries, parallel qgen. R10's qgen was 32 blocks (1/batch,
// 1.4% occupancy, ~100us each). Now grid (16 l-chunks x 32 b) = 512 blocks,
// R6-k_fused structure: stage scale-(i-1) segments + halo, w48 matvecs in
// LDS, incremental fhat_ws update, atomicAdd(-sum) into restAll query slices
// pre-initialized with hierarchical F-sums by prep. No Sb/EL/ER state.
// argmax (R6-proven) and k_final (R10-proven) unchanged.

#define B_ 32
#define C_ 64
#define L_ 512
#define V_ 8192

typedef _Float16 half8 __attribute__((ext_vector_type(8)));
typedef float f32x4 __attribute__((ext_vector_type(4)));

#define C11 4.8828125e-4f  // 2^-11

__device__ __forceinline__ unsigned enc_f(float s) {
  unsigned u = __float_as_uint(s);
  return (u & 0x80000000u) ? ~u : (u | 0x80000000u);
}

__device__ __forceinline__ void split2(float x, _Float16& h, _Float16& m) {
  h = (_Float16)x;
  float r1 = x - (float)h;       // exact
  m = (_Float16)(r1 * 2048.0f);  // scaled into fp16 normal range
}

// ---------- prep: codebook split + hierarchical F-sums into restAll + zero ----------
__global__ __launch_bounds__(256) void k_prep(
    const float* __restrict__ f, const float* __restrict__ embed,
    _Float16* __restrict__ ch, _Float16* __restrict__ cm,
    float* __restrict__ restAll, float* __restrict__ lossac,
    unsigned long long* __restrict__ packed) {
  const int blk = blockIdx.x;
  const int tid = threadIdx.x;
  if (blk < 128) {
    // normalize codebook rows (fp32), 2-way split, [V][64]
    int g = blk * 256 + tid;
    int v = g >> 2;
    int sub = g & 3;
    const float* row = embed + v * 64 + sub * 16;
    float x[16];
    float ss = 0.f;
#pragma unroll
    for (int i = 0; i < 16; i += 4) {
      float4 t = *(const float4*)(row + i);
      x[i] = t.x; x[i + 1] = t.y; x[i + 2] = t.z; x[i + 3] = t.w;
      ss += t.x * t.x + t.y * t.y + t.z * t.z + t.w * t.w;
    }
    ss += __shfl_xor(ss, 1);
    ss += __shfl_xor(ss, 2);
    float rinv = 1.0f / fmaxf(sqrtf(ss), 1e-12f);
    _Float16 hb[16], mb[16];
#pragma unroll
    for (int i = 0; i < 16; i++) split2(x[i] * rinv, hb[i], mb[i]);
    const int o = v * 64 + sub * 16;
    *(half8*)(ch + o) = *(half8*)(hb);
    *(half8*)(ch + o + 8) = *(half8*)(hb + 8);
    *(half8*)(cm + o) = *(half8*)(mb);
    *(half8*)(cm + o + 8) = *(half8*)(mb + 8);
  } else if (blk < 640) {
    // hierarchical sums of f for ALL scales -> restAll slices; one wave/(b,c)
    int gw = (blk - 128) * 4 + (tid >> 6);  // [0,2048)
    int b = gw >> 6;
    int c = gw & 63;
    int lane = tid & 63;
    const float* row = f + (b * 64 + c) * 512 + lane * 8;
    float4 x0 = *(const float4*)row;
    float4 x1 = *(const float4*)(row + 4);
    {  // s=512
      int base = 1046528 + c * 16384 + b * 512 + lane * 8;
      *(float4*)(restAll + base) = x0;
      *(float4*)(restAll + base + 4) = x1;
    }
    {  // s=256
      int base = 522240 + c * 8192 + b * 256 + lane * 4;
      restAll[base + 0] = x0.x + x0.y;
      restAll[base + 1] = x0.z + x0.w;
      restAll[base + 2] = x1.x + x1.y;
      restAll[base + 3] = x1.z + x1.w;
    }
    float y0 = (x0.x + x0.y) + (x0.z + x0.w);
    float y1 = (x1.x + x1.y) + (x1.z + x1.w);
    {  // s=128
      int base = 260096 + c * 4096 + b * 128 + lane * 2;
      restAll[base + 0] = y0;
      restAll[base + 1] = y1;
    }
    float v6 = y0 + y1;
    restAll[129024 + c * 2048 + b * 64 + lane] = v6;  // s=64
    float v5 = v6 + __shfl_xor(v6, 1);
    if (!(lane & 1)) restAll[63488 + c * 1024 + b * 32 + (lane >> 1)] = v5;
    float v4 = v5 + __shfl_xor(v5, 2);
    if (!(lane & 3)) restAll[30720 + c * 512 + b * 16 + (lane >> 2)] = v4;
    float v3 = v4 + __shfl_xor(v4, 4);
    if (!(lane & 7)) restAll[14336 + c * 256 + b * 8 + (lane >> 3)] = v3;
    float v2 = v3 + __shfl_xor(v3, 8);
    if (!(lane & 15)) restAll[6144 + c * 128 + b * 4 + (lane >> 4)] = v2;
    float v1 = v2 + __shfl_xor(v2, 16);
    if (!(lane & 31)) restAll[2048 + c * 64 + b * 2 + (lane >> 5)] = v1;
    float v0 = v1 + __shfl_xor(v1, 32);
    if (lane == 0) restAll[c * 32 + b] = v0;
  } else {
    // zero packed + lossac
    int zg = (blk - 640) * 256 + tid;
    const int ZS = 32 * 256;
    for (int i = zg; i < 32736; i += ZS) packed[i] = 0ull;
    if (zg < 16) lossac[zg] = 0.0f;
  }
}

// ---------- MFMA argmax (R6 body, unchanged) ----------
template <int MT>
__global__ __launch_bounds__(256) void k_argmax3(
    const _Float16* __restrict__ ch, const _Float16* __restrict__ cm,
    const float* __restrict__ restq, unsigned long long* __restrict__ packedq,
    int Q, int mgroups, int wave_codes) {
  const int mg = blockIdx.x % mgroups;
  const int sp = blockIdx.x / mgroups;
  const int lane = threadIdx.x & 63;
  const int wave = threadIdx.x >> 6;
  const int qbase = mg * (MT * 16);
  __shared__ _Float16 qh[MT * 16][72];
  __shared__ _Float16 qm[MT * 16][72];
  for (int i = threadIdx.x; i < MT * 16 * 64; i += 256) {
    int c = i / (MT * 16);
    int qq = i % (MT * 16);
    float v = restq[c * Q + qbase + qq];
    _Float16 h, m;
    split2(v, h, m);
    qh[qq][c] = h;
    qm[qq][c] = m;
  }
  __syncthreads();

  const int m = lane & 15;
  const int quad = lane >> 4;
  half8 ah[MT][2], am[MT][2];
#pragma unroll
  for (int mt = 0; mt < MT; mt++)
#pragma unroll
    for (int kc = 0; kc < 2; kc++) {
      ah[mt][kc] = *(const half8*)(&qh[mt * 16 + m][kc * 32 + quad * 8]);
      am[mt][kc] = *(const half8*)(&qm[mt * 16 + m][kc * 32 + quad * 8]);
    }

  float best[MT][4];
  int bidx[MT][4];
#pragma unroll
  for (int mt = 0; mt < MT; mt++)
#pragma unroll
    for (int r = 0; r < 4; r++) { best[mt][r] = -3.4e38f; bidx[mt][r] = 0; }

  const int code_start = (sp * 4 + wave) * wave_codes;
  const _Float16* ph = ch + (code_start + m) * 64 + quad * 8;
  const _Float16* pm = cm + (code_start + m) * 64 + quad * 8;
  half8 nbh0 = *(const half8*)(ph);
  half8 nbh1 = *(const half8*)(ph + 32);
  half8 nbm0 = *(const half8*)(pm);
  half8 nbm1 = *(const half8*)(pm + 32);
  for (int t = 0; t < wave_codes; t += 16) {
    const half8 bh0 = nbh0, bh1 = nbh1, bm0 = nbm0, bm1 = nbm1;
    if (t + 16 < wave_codes) {
      ph += 16 * 64;
      pm += 16 * 64;
      nbh0 = *(const half8*)(ph);
      nbh1 = *(const half8*)(ph + 32);
      nbm0 = *(const half8*)(pm);
      nbm1 = *(const half8*)(pm + 32);
    }
    const int cid = code_start + t + m;
#pragma unroll
    for (int mt = 0; mt < MT; mt++) {
      f32x4 a0 = {0.f, 0.f, 0.f, 0.f};
      f32x4 a1 = {0.f, 0.f, 0.f, 0.f};
      a0 = __builtin_amdgcn_mfma_f32_16x16x32_f16(ah[mt][0], bh0, a0, 0, 0, 0);
      a1 = __builtin_amdgcn_mfma_f32_16x16x32_f16(ah[mt][0], bm0, a1, 0, 0, 0);
      a1 = __builtin_amdgcn_mfma_f32_16x16x32_f16(am[mt][0], bh0, a1, 0, 0, 0);
      a0 = __builtin_amdgcn_mfma_f32_16x16x32_f16(ah[mt][1], bh1, a0, 0, 0, 0);
      a1 = __builtin_amdgcn_mfma_f32_16x16x32_f16(ah[mt][1], bm1, a1, 0, 0, 0);
      a1 = __builtin_amdgcn_mfma_f32_16x16x32_f16(am[mt][1], bh1, a1, 0, 0, 0);
#pragma unroll
      for (int r = 0; r < 4; r++) {
        float sc = fmaf(C11, a1[r], a0[r]);
        if (sc > best[mt][r]) { best[mt][r] = sc; bidx[mt][r] = cid; }
      }
    }
  }
#pragma unroll
  for (int off = 1; off < 16; off <<= 1) {
#pragma unroll
    for (int mt = 0; mt < MT; mt++)
#pragma unroll
      for (int r = 0; r < 4; r++) {
        float ob = __shfl_xor(best[mt][r], off);
        int oi = __shfl_xor(bidx[mt][r], off);
        if (ob > best[mt][r] || (ob == best[mt][r] && oi < bidx[mt][r])) {
          best[mt][r] = ob; bidx[mt][r] = oi;
        }
      }
  }
  if (m == 0) {
#pragma unroll
    for (int mt = 0; mt < MT; mt++)
#pragma unroll
      for (int r = 0; r < 4; r++) {
        unsigned long long pk =
            ((unsigned long long)enc_f(best[mt][r]) << 32) |
            (unsigned)(~bidx[mt][r]);
        atomicMax(&packedq[qbase + mt * 16 + quad * 4 + r], pk);
      }
  }
}

// ---------- qgen2: apply scale k=i-1 to fhat_ws tile, emit scale-i queries ----------
__global__ __launch_bounds__(256) void k_qgen2(
    const float* __restrict__ embed, const float* __restrict__ phiw,
    const float* __restrict__ phib,
    const unsigned long long* __restrict__ packed, float* __restrict__ restAll,
    float* __restrict__ fhat_ws, int i, int pk_) {
  const int ch0 = blockIdx.x * 32;
  const int bb = blockIdx.y;
  const int tid = threadIdx.x;
  const int k = i - 1;
  const int sk = 1 << k;
  const int log2blkk = 9 - k;
  const int blkw = 1 << log2blkk;
  int j_lo = (ch0 >> log2blkk) - 1;
  if (j_lo < 0) j_lo = 0;
  int j_hi = ((ch0 + 31) >> log2blkk) + 1;
  if (j_hi > sk - 1) j_hi = sk - 1;
  const int nseg = j_hi - j_lo + 1;  // <= 18

  __shared__ float hl[18][64];
  __shared__ float abc_l[18][192];

  for (int idx = tid; idx < nseg * 64; idx += 256) {
    int seg = idx >> 6, c = idx & 63;
    int w = (int)(~(unsigned)(packed[32 * (sk - 1) + bb * sk + j_lo + seg]));
    hl[seg][c] = embed[w * 64 + c];
  }
  __syncthreads();

  // matvec (R6 w48 scheme): lane o = out channel, 4 waves stride segments
  {
    const int o = tid & 63;
    const int w4 = tid >> 6;
    const float* wrow = phiw + (pk_ * 64 + o) * 192;
    float acc[5][3];
#pragma unroll
    for (int a = 0; a < 5; a++) { acc[a][0] = acc[a][1] = acc[a][2] = 0.f; }
#pragma unroll
    for (int c4b = 0; c4b < 4; c4b++) {
      float w48[48];
#pragma unroll
      for (int kk = 0; kk < 12; kk++)
        *(float4*)(w48 + 4 * kk) = *(const float4*)(wrow + c4b * 48 + 4 * kk);
#pragma unroll
      for (int sx = 0; sx < 5; sx++) {
        int seg = w4 + sx * 4;
        if (seg < nseg) {
#pragma unroll
          for (int cc4 = 0; cc4 < 4; cc4++) {
            float4 h4 = *(const float4*)(&hl[seg][c4b * 16 + cc4 * 4]);
            const float hv[4] = {h4.x, h4.y, h4.z, h4.w};
#pragma unroll
            for (int u = 0; u < 4; u++) {
              int cc = cc4 * 4 + u;
              acc[sx][0] = fmaf(w48[cc * 3 + 0], hv[u], acc[sx][0]);
              acc[sx][1] = fmaf(w48[cc * 3 + 1], hv[u], acc[sx][1]);
              acc[sx][2] = fmaf(w48[cc * 3 + 2], hv[u], acc[sx][2]);
            }
          }
        }
      }
    }
#pragma unroll
    for (int sx = 0; sx < 5; sx++) {
      int seg = w4 + sx * 4;
      if (seg < nseg) {
        abc_l[seg][o] = acc[sx][0];
        abc_l[seg][64 + o] = acc[sx][1];
        abc_l[seg][128 + o] = acc[sx][2];
      }
    }
  }
  __syncthreads();

  // apply scale k to fhat_ws: thread = (c, 8 consecutive l)
  const int c = tid >> 2;
  const int l0 = ch0 + (tid & 3) * 8;
  const float bias = phib[pk_ * 64 + c];
  const int fi0 = (bb * 64 + c) * 512 + l0;
  float fhv[8] = {0.f, 0.f, 0.f, 0.f, 0.f, 0.f, 0.f, 0.f};
  if (k != 0) {
    const float4 ga = *(const float4*)(fhat_ws + fi0);
    const float4 gb = *(const float4*)(fhat_ws + fi0 + 4);
    fhv[0] = ga.x; fhv[1] = ga.y; fhv[2] = ga.z; fhv[3] = ga.w;
    fhv[4] = gb.x; fhv[5] = gb.y; fhv[6] = gb.z; fhv[7] = gb.w;
  }
#pragma unroll
  for (int t = 0; t < 8; t++) {
    int l = l0 + t;
    int j = l >> log2blkk;
    int jrel = j - j_lo;
    int pos = l & (blkw - 1);
    float y = abc_l[jrel][64 + c] + bias;
    if (pos == 0) {
      if (j > 0) y += abc_l[jrel - 1][c];
    } else {
      y += abc_l[jrel][c];
    }
    if (pos == blkw - 1) {
      if (j < sk - 1) y += abc_l[jrel + 1][128 + c];
    } else {
      y += abc_l[jrel][128 + c];
    }
    fhv[t] += 0.5f * (hl[jrel][c] + y);
  }
  *(float4*)(fhat_ws + fi0) = make_float4(fhv[0], fhv[1], fhv[2], fhv[3]);
  *(float4*)(fhat_ws + fi0 + 4) = make_float4(fhv[4], fhv[5], fhv[6], fhv[7]);

  // emit scale-i query partials: q = Fsum (pre-init) - sum(fhat over block)
  const int si_ = 1 << i;
  const int log2blki = 9 - i;
  const int blki = 1 << log2blki;
  const int Q = 32 * si_;
  float* rq = restAll + 2048 * (si_ - 1) + c * Q + bb * si_;
  if (blki >= 8) {
    float ssum = (((fhv[0] + fhv[1]) + (fhv[2] + fhv[3])) +
                  ((fhv[4] + fhv[5]) + (fhv[6] + fhv[7])));
    atomicAdd(&rq[l0 >> log2blki], -ssum);
  } else {
    for (int base = 0; base < 8; base += blki) {
      float ssum = 0.f;
      for (int t = 0; t < blki; t++) ssum += fhv[base + t];
      atomicAdd(&rq[(l0 + base) >> log2blki], -ssum);
    }
  }
}

// ---------- final: materialize fhat (registers) + all 10 losses (R10 body) ----------
__global__ __launch_bounds__(256) void k_final(
    const float* __restrict__ f, const float* __restrict__ embed,
    const float* __restrict__ phiw, const float* __restrict__ phib,
    const unsigned long long* __restrict__ packed, float* __restrict__ fhat,
    float* __restrict__ lossac) {
  const int ch0 = blockIdx.x * 64;
  const int bb = blockIdx.y;
  const int tid = threadIdx.x;
  __shared__ float hl[66][64];
  __shared__ float abc_l[66][192];
  __shared__ float red[4];

  const int c = tid >> 2;
  const int l0 = ch0 + (tid & 3) * 16;
  const int fi0 = (bb * 64 + c) * 512 + l0;
  float fv[16], fh[16];
#pragma unroll
  for (int t = 0; t < 4; t++) {
    float4 x = *(const float4*)(f + fi0 + t * 4);
    fv[t * 4] = x.x; fv[t * 4 + 1] = x.y; fv[t * 4 + 2] = x.z;
    fv[t * 4 + 3] = x.w;
  }
#pragma unroll
  for (int t = 0; t < 16; t++) fh[t] = 0.f;

  static const int PIDXd[10] = {0, 0, 1, 1, 1, 2, 2, 3, 3, 3};
  const int lane = tid & 63, wave = tid >> 6;

#pragma unroll 1
  for (int k = 0; k < 10; k++) {
    const int s = 1 << k;
    const int log2blk = 9 - k;
    const int blkw = 1 << log2blk;
    const int p = PIDXd[k];
    int j_lo = (ch0 >> log2blk) - 1;
    if (j_lo < 0) j_lo = 0;
    int j_hi = ((ch0 + 63) >> log2blk) + 1;
    if (j_hi > s - 1) j_hi = s - 1;
    const int nseg = j_hi - j_lo + 1;  // <= 66

    __syncthreads();
    for (int idx = tid; idx < nseg * 64; idx += 256) {
      int seg = idx >> 6, cc = idx & 63;
      int w = (int)(~(unsigned)(packed[32 * (s - 1) + bb * s + j_lo + seg]));
      hl[seg][cc] = embed[w * 64 + cc];
    }
    __syncthreads();

    {
      const int o = tid & 63;
      const float* wrow = phiw + (p * 64 + o) * 192;
      for (int seg = tid >> 6; seg < nseg; seg += 4) {
        float a0 = 0.f, a1 = 0.f, a2 = 0.f;
#pragma unroll
        for (int c4b = 0; c4b < 4; c4b++) {
          float w48[48];
#pragma unroll
          for (int kk = 0; kk < 12; kk++)
            *(float4*)(w48 + 4 * kk) =
                *(const float4*)(wrow + c4b * 48 + 4 * kk);
#pragma unroll
          for (int cc4 = 0; cc4 < 4; cc4++) {
            float4 h4 = *(const float4*)(&hl[seg][c4b * 16 + cc4 * 4]);
            const float hv[4] = {h4.x, h4.y, h4.z, h4.w};
#pragma unroll
            for (int u = 0; u < 4; u++) {
              int cc = cc4 * 4 + u;
              a0 = fmaf(w48[cc * 3 + 0], hv[u], a0);
              a1 = fmaf(w48[cc * 3 + 1], hv[u], a1);
              a2 = fmaf(w48[cc * 3 + 2], hv[u], a2);
            }
          }
        }
        abc_l[seg][o] = a0;
        abc_l[seg][64 + o] = a1;
        abc_l[seg][128 + o] = a2;
      }
    }
    __syncthreads();

    const float bias = phib[p * 64 + c];
    float sq = 0.f;
#pragma unroll
    for (int t = 0; t < 16; t++) {
      int l = l0 + t;
      int j = l >> log2blk;
      int jrel = j - j_lo;
      int pos = l & (blkw - 1);
      float y = abc_l[jrel][64 + c] + bias;
      if (pos == 0) {
        if (j > 0) y += abc_l[jrel - 1][c];
      } else {
        y += abc_l[jrel][c];
      }
      if (pos == blkw - 1) {
        if (j < s - 1) y += abc_l[jrel + 1][128 + c];
      } else {
        y += abc_l[jrel][128 + c];
      }
      fh[t] += 0.5f * (hl[jrel][c] + y);
      float d = fh[t] - fv[t];
      sq = fmaf(d, d, sq);
    }
#pragma unroll
    for (int off = 32; off > 0; off >>= 1) sq += __shfl_down(sq, off);
    if (lane == 0) red[wave] = sq;
    __syncthreads();
    if (tid == 0)
      atomicAdd(&lossac[k], (red[0] + red[1]) + (red[2] + red[3]));
  }

#pragma unroll
  for (int t = 0; t < 4; t++)
    *(float4*)(fhat + fi0 + t * 4) =
        make_float4(fh[t * 4], fh[t * 4 + 1], fh[t * 4 + 2], fh[t * 4 + 3]);
}

// ---------- final loss scalar ----------
__global__ void k_loss(const float* __restrict__ lossac,
                       float* __restrict__ out) {
  if (threadIdx.x == 0 && blockIdx.x == 0) {
    float sum = 0.f;
    for (int i = 0; i < 10; i++) sum += lossac[i];
    out[B_ * C_ * L_] = sum * (1.25f / (10.0f * (float)(B_ * C_ * L_)));
  }
}

extern "C" void kernel_launch(void* const* d_in, const int* in_sizes, int n_in,
                              void* d_out, int out_size, void* d_ws,
                              size_t ws_size, hipStream_t stream) {
  const float* f     = (const float*)d_in[0];  // [32][64][512]
  const float* embed = (const float*)d_in[1];  // [8192][64]
  const float* phiw  = (const float*)d_in[2];  // [4][64][64][3]
  const float* phib  = (const float*)d_in[3];  // [4][64]
  float* fhat = (float*)d_out;                 // f_hat + loss at [1048576]

  float* restAll = (float*)d_ws;                    // 2,095,104 floats
  float* fhat_ws = restAll + 2095104;               // 1,048,576
  float* lossac  = fhat_ws + 1048576;               // 16
  unsigned long long* packed = (unsigned long long*)(lossac + 16);  // 32736
  _Float16* ch = (_Float16*)(packed + 32736);       // V*64
  _Float16* cm = ch + V_ * 64;                      // V*64

  static const int PIDX[10] = {0, 0, 1, 1, 1, 2, 2, 3, 3, 3};
  static const int NSPL[10] = {128, 128, 128, 64, 64, 32, 16, 16, 8, 4};

  k_prep<<<dim3(672), dim3(256), 0, stream>>>(f, embed, ch, cm, restAll,
                                              lossac, packed);

  for (int si = 0; si < 10; si++) {
    const int s = 1 << si;
    const int Q = 32 * s;
    const int nsplit = NSPL[si];
    const int wave_codes = 2048 / nsplit;
    unsigned long long* pq = packed + 32 * (s - 1);
    if (si > 0) {
      k_qgen2<<<dim3(16, 32), dim3(256), 0, stream>>>(
          embed, phiw, phib, packed, restAll, fhat_ws, si, PIDX[si - 1]);
    }
    const float* restq = restAll + 2048 * (s - 1);
    if (Q >= 64) {
      const int mgroups = Q / 64;
      k_argmax3<4><<<dim3(mgroups * nsplit), dim3(256), 0, stream>>>(
          ch, cm, restq, pq, Q, mgroups, wave_codes);
    } else {
      k_argmax3<2><<<dim3(nsplit), dim3(256), 0, stream>>>(
          ch, cm, restq, pq, Q, 1, wave_codes);
    }
  }

  k_final<<<dim3(8, 32), dim3(256), 0, stream>>>(f, embed, phiw, phib, packed,
                                                 fhat, lossac);
  k_loss<<<dim3(1), dim3(64), 0, stream>>>(lossac, fhat);
}